// Round 11
// baseline (193.270 us; speedup 1.0000x reference)
//
#include <hip/hip_runtime.h>
#include <math.h>

#define B_ 256
#define T_ 2048
#define N_ 17
#define LOG2E 1.44269504088896340736f
#define LN2   0.69314718055994530942f
#define QROW 24          // shorts per stored Q row
#define QMAT 416         // shorts per stored Q matrix

typedef short bf16x8 __attribute__((ext_vector_type(8)));
typedef float f32x16 __attribute__((ext_vector_type(16)));
typedef float v2f __attribute__((ext_vector_type(2)));

__device__ __forceinline__ float rlf(float v, int i) {
    return __int_as_float(__builtin_amdgcn_readlane(__float_as_int(v), i));
}
__device__ __forceinline__ float fexp2(float x) {
    float r;
    asm("v_exp_f32 %0, %1" : "=v"(r) : "v"(x));
    return r;
}
__device__ __forceinline__ float fmax3(float a, float b, float c) {
    return fmaxf(fmaxf(a, b), c);
}
// pack two f32 into bf16x2 (truncation — products are positive, bias tiny)
__device__ __forceinline__ unsigned pack_bf16(float lo, float hi) {
    return __builtin_amdgcn_perm(__float_as_uint(hi), __float_as_uint(lo), 0x07060302u);
}

// ---------------- kernel 1: build 17x17 log-transition matrix ----------------
__global__ __launch_bounds__(256) void build_trans_k(
    const float* __restrict__ hiddens, const float* __restrict__ p_in,
    const float* __restrict__ p_cross, const float* __restrict__ p_out,
    const float* __restrict__ p_to_out, const float* __restrict__ p_from_out,
    const float* __restrict__ w_attn, const float* __restrict__ b_attn,
    float* __restrict__ trans)
{
    __shared__ float partial[32][8];
    __shared__ float att[8][4];
    int tid = threadIdx.x;
    int pair = tid >> 3, sub = tid & 7;
    int e = pair >> 2, a = pair & 3;
    float acc = 0.f;
    for (int h = sub; h < 768; h += 8)
        acc += hiddens[e*768 + h] * w_attn[h*4 + a];
    partial[pair][sub] = acc;
    __syncthreads();
    if (tid < 32) {
        float s = 0.f;
        for (int k2 = 0; k2 < 8; ++k2) s += partial[tid][k2];
        att[tid>>2][tid&3] = s + b_attn[tid&3];
    }
    __syncthreads();
    if (tid == 0) {
        float t1[8][4], t2[8][4];
        for (int a2 = 0; a2 < 4; ++a2) {
            float m = -1e30f;
            for (int e2 = 0; e2 < 8; ++e2) m = fmaxf(m, att[e2][a2]);
            float s = 0.f;
            for (int e2 = 0; e2 < 8; ++e2) { t1[e2][a2] = expf(att[e2][a2] - m); s += t1[e2][a2]; }
            for (int e2 = 0; e2 < 8; ++e2) t1[e2][a2] /= s;
        }
        for (int e2 = 0; e2 < 8; ++e2) {
            float m = -1e30f;
            for (int a2 = 0; a2 < 4; ++a2) m = fmaxf(m, t1[e2][a2]*10.f);
            float s = 0.f;
            for (int a2 = 0; a2 < 4; ++a2) { t2[e2][a2] = expf(t1[e2][a2]*10.f - m); s += t2[e2][a2]; }
            for (int a2 = 0; a2 < 4; ++a2) t2[e2][a2] /= s;
        }
        trans[0] = p_out[0];
        for (int c = 0; c < 16; ++c) trans[0*N_ + 1 + c] = p_from_out[c & 1];
        for (int r = 0; r < 16; ++r) trans[(1+r)*N_ + 0] = p_to_out[r & 1];
        for (int eb = 0; eb < 8; ++eb)
        for (int r = 0; r < 2; ++r)
        for (int ec = 0; ec < 8; ++ec)
        for (int c = 0; c < 2; ++c) {
            float v;
            if (eb == ec) {
                v = 0.f;
                for (int a2 = 0; a2 < 4; ++a2) v += p_in[a2*4 + r*2 + c] * t2[eb][a2];
                v *= 0.25f;
            } else v = p_cross[r*2 + c];
            trans[(1 + eb*2 + r)*N_ + (1 + ec*2 + c)] = v;
        }
    }
}

// ---------------- kernel 2: phase A — per-chunk product matrices via MFMA ----
// EXACT R8/R10-proven step body. Only change: __launch_bounds__(64, 4) so the
// MFMA dest need not alias its zero-C operand (kills the 16-reg fz copy/step).
__device__ __forceinline__ f32x16 pa_step(
    const f32x16& acc, const f32x16& fz, float ev, int mv,
    const v2f* TA, float TA8x, const unsigned* ia1u, unsigned ia2u0, int h)
{
    float e = fexp2(ev * LOG2E);
    v2f ee; ee.x = e; ee.y = e;
    v2f s0 = TA[0]*ee, s1 = TA[1]*ee, s2 = TA[2]*ee, s3 = TA[3]*ee;
    float s8x = TA8x * e;
    bool upd = __builtin_amdgcn_readfirstlane(mv) > 0;
    union { unsigned u[4]; bf16x8 v; } a1, a2, b1, b2;
    a1.u[0] = upd ? pack_bf16(s0.x, s0.y) : ia1u[0];
    a1.u[1] = upd ? pack_bf16(s1.x, s1.y) : ia1u[1];
    a1.u[2] = upd ? pack_bf16(s2.x, s2.y) : ia1u[2];
    a1.u[3] = upd ? pack_bf16(s3.x, s3.y) : ia1u[3];
    a2.u[0] = upd ? pack_bf16(s8x, 0.f) : ia2u0;
    a2.u[1] = 0; a2.u[2] = 0; a2.u[3] = 0;
    unsigned p89 = pack_bf16(acc[8], 0.f);
    b2.u[0] = (h == 0) ? p89 : 0u;
    b2.u[1] = 0; b2.u[2] = 0; b2.u[3] = 0;
    float x0=acc[0], x1=acc[1], x2=acc[2], x3=acc[3];
    float x4=acc[4], x5=acc[5], x6=acc[6], x7=acc[7];
    asm("v_permlane32_swap_b32 %0, %1" : "+v"(x4), "+v"(x0));
    asm("v_permlane32_swap_b32 %0, %1" : "+v"(x5), "+v"(x1));
    asm("v_permlane32_swap_b32 %0, %1" : "+v"(x6), "+v"(x2));
    asm("v_permlane32_swap_b32 %0, %1" : "+v"(x7), "+v"(x3));
    b1.u[0] = pack_bf16(x0, x1);
    b1.u[1] = pack_bf16(x2, x3);
    b1.u[2] = pack_bf16(x4, x5);
    b1.u[3] = pack_bf16(x6, x7);
    f32x16 d = __builtin_amdgcn_mfma_f32_32x32x16_bf16(a1.v, b1.v, fz, 0, 0, 0);
    d = __builtin_amdgcn_mfma_f32_32x32x16_bf16(a2.v, b2.v, d, 0, 0, 0);
    return d;
}

template <int NCH>
__global__ __launch_bounds__(64, 4) void phaseA_k(
    const float* __restrict__ inputs, const int* __restrict__ mask,
    const float* __restrict__ trans, unsigned short* __restrict__ Qout,
    int* __restrict__ Kout)
{
    constexpr int CL = T_ / NCH;
    constexpr int GR = CL / 8;
    const int gid = blockIdx.x;
    const int b = gid / NCH;
    const int c = gid % NCH;
    const int lane = threadIdx.x & 63;
    const int n = lane & 31;
    const int h = lane >> 5;

    v2f TA[4];
    #pragma unroll
    for (int r2 = 0; r2 < 4; ++r2) {
        int k0 = 8*h + 2*r2;
        TA[r2].x = (n < N_ && k0   < N_) ? expf(trans[k0*N_ + n])     : 0.f;
        TA[r2].y = (n < N_ && k0+1 < N_) ? expf(trans[(k0+1)*N_ + n]) : 0.f;
    }
    float TA8x = (n < N_ && h == 0) ? expf(trans[16*N_ + n]) : 0.f;

    unsigned ia1u[4];
    #pragma unroll
    for (int r2 = 0; r2 < 4; ++r2) {
        int k0 = 8*h + 2*r2;
        ia1u[r2] = pack_bf16(n == k0 ? 1.f : 0.f, n == k0+1 ? 1.f : 0.f);
    }
    unsigned ia2u0 = (n == 16 && h == 0) ? pack_bf16(1.f, 0.f) : 0u;

    f32x16 acc;
    #pragma unroll
    for (int r = 0; r < 16; ++r) {
        int R = (r & 3) + 8*(r >> 2) + 4*h;
        acc[r] = (R == n) ? 1.f : 0.f;
    }
    f32x16 fz;
    #pragma unroll
    for (int r = 0; r < 16; ++r) fz[r] = 0.f;

    const int t0 = c * CL;
    const float* ep = inputs + (size_t)b*T_*N_ + (n < N_ ? n : N_-1);
    const int*   mp = mask + (size_t)b*T_;

    float re[8]; int rm[8];
    #pragma unroll
    for (int p = 0; p < 8; ++p) {
        int t = t0 + p;
        re[p] = ep[(size_t)t * N_];
        rm[p] = (t == 0) ? 0 : mp[t];
    }
    const float* epn = ep + (size_t)(t0 + 8) * N_;
    const int*   mpn = mp + (t0 + 8);
    int K = 0;

#define PA_RESCALE                                                             \
    {                                                                          \
        float mxa = fmax3(acc[0], acc[1], acc[2]);                             \
        float mxb = fmax3(acc[3], acc[4], acc[5]);                             \
        float mx  = fmax3(acc[6], acc[7], acc[8]);                             \
        mx = fmax3(mx, mxa, mxb);                                              \
        _Pragma("unroll")                                                      \
        for (int off = 32; off > 0; off >>= 1)                                 \
            mx = fmaxf(mx, __shfl_xor(mx, off, 64));                           \
        int sexp = (int)(__float_as_uint(mx) >> 23) - 127;                     \
        float sc = __uint_as_float((unsigned)(127 - sexp) << 23);              \
        v2f scv; scv.x = sc; scv.y = sc;                                       \
        _Pragma("unroll")                                                      \
        for (int r = 0; r < 4; ++r) {                                          \
            v2f pr; pr.x = acc[2*r]; pr.y = acc[2*r+1];                        \
            pr = pr * scv;                                                     \
            acc[2*r] = pr.x; acc[2*r+1] = pr.y;                                \
        }                                                                      \
        acc[8] *= sc;                                                          \
        K += sexp;                                                             \
    }

    for (int g = 0; g < GR - 1; ++g) {
        #pragma unroll
        for (int u = 0; u < 8; ++u) {
            float ev = re[u]; int mv = rm[u];
            re[u] = epn[u * N_];
            rm[u] = mpn[u];
            acc = pa_step(acc, fz, ev, mv, TA, TA8x, ia1u, ia2u0, h);
        }
        epn += 8 * N_; mpn += 8;
        PA_RESCALE
    }
    #pragma unroll
    for (int u = 0; u < 8; ++u) {
        float ev = re[u]; int mv = rm[u];
        acc = pa_step(acc, fz, ev, mv, TA, TA8x, ia1u, ia2u0, h);
    }
    PA_RESCALE

    unsigned short* qb = Qout + (size_t)gid * QMAT;
    #pragma unroll
    for (int r = 0; r < 9; ++r) {
        int R = (r & 3) + 8*(r >> 2) + 4*h;
        if (R < N_ && n < N_)
            qb[R*QROW + n] = (unsigned short)(__float_as_uint(acc[r]) >> 16);
    }
    if (lane == 0) Kout[gid] = K;
}

// ---------------- kernel 3: fused tail — numer partials + combine + output ---
__global__ __launch_bounds__(256) void tail_k(
    const float* __restrict__ inputs, const int* __restrict__ tags,
    const int* __restrict__ mask, const float* __restrict__ trans,
    const unsigned short* __restrict__ Qin, const int* __restrict__ Kin,
    float* __restrict__ out, int nch)
{
    const int b = blockIdx.x, tid = threadIdx.x;
    const int* tg = tags + (size_t)b * T_;
    const int* mp = mask + (size_t)b * T_;
    const float* ip = inputs + (size_t)b * T_ * N_;

    // ---- numerator partial sums (all 256 threads) ----
    float tsum = 0.f, esum = 0.f; int msum = 0;
    for (int t = tid; t < T_ - 1; t += 256) {
        int g = tg[t], g2 = tg[t+1];
        int m1 = mp[t], m2 = mp[t+1];
        tsum += (m2 > 0) ? trans[g*N_ + g2] : 0.f;
        esum += (m1 > 0) ? ip[(size_t)t*N_ + g] : 0.f;
        msum += (m1 > 0) ? 1 : 0;
    }
    if (tid == 0) msum += (mp[T_-1] > 0) ? 1 : 0;
    #pragma unroll
    for (int off = 32; off > 0; off >>= 1) {
        tsum += __shfl_xor(tsum, off, 64);
        esum += __shfl_xor(esum, off, 64);
        msum += __shfl_xor(msum, off, 64);
    }
    __shared__ float r0[4], r1[4]; __shared__ int r2[4];
    __shared__ float s_denom;
    int wid = tid >> 6;
    if ((tid & 63) == 0) { r0[wid] = tsum; r1[wid] = esum; r2[wid] = msum; }
    __syncthreads();

    // ---- combine chunk matrices (wave 0 only) ----
    if (tid < 64) {
        const int lane = tid;
        const bool active = lane < N_;
        const int j = active ? lane : N_-1;
        float a0 = active ? ip[j] : -1e30f;
        float m0 = rlf(a0, 0);
        #pragma unroll
        for (int i = 1; i < N_; ++i) m0 = fmaxf(m0, rlf(a0, i));
        float w = active ? fexp2((a0 - m0)*LOG2E) : 0.f;
        int K = 0;
        for (int c = 0; c < nch; ++c) {
            const unsigned short* qr = Qin + (size_t)(b*nch + c)*QMAT + j*QROW;
            uint4 qa = *(const uint4*)qr;
            uint4 qc4 = *(const uint4*)(qr + 8);
            unsigned q16u = qr[16];
            int kc = Kin[b*nch + c];
            float sv[N_];
            #pragma unroll
            for (int i = 0; i < N_; ++i) sv[i] = rlf(w, i);
            unsigned mxb = __float_as_uint(sv[0]);
            #pragma unroll
            for (int i = 1; i < N_; ++i) { unsigned bi = __float_as_uint(sv[i]); if (bi > mxb) mxb = bi; }
            int me = (int)(mxb >> 23) - 127;
            float sc = __uint_as_float((unsigned)(127 - me) << 23);
            float q[N_];
            q[0]  = __uint_as_float(qa.x << 16);  q[1]  = __uint_as_float(qa.x & 0xFFFF0000u);
            q[2]  = __uint_as_float(qa.y << 16);  q[3]  = __uint_as_float(qa.y & 0xFFFF0000u);
            q[4]  = __uint_as_float(qa.z << 16);  q[5]  = __uint_as_float(qa.z & 0xFFFF0000u);
            q[6]  = __uint_as_float(qa.w << 16);  q[7]  = __uint_as_float(qa.w & 0xFFFF0000u);
            q[8]  = __uint_as_float(qc4.x << 16); q[9]  = __uint_as_float(qc4.x & 0xFFFF0000u);
            q[10] = __uint_as_float(qc4.y << 16); q[11] = __uint_as_float(qc4.y & 0xFFFF0000u);
            q[12] = __uint_as_float(qc4.z << 16); q[13] = __uint_as_float(qc4.z & 0xFFFF0000u);
            q[14] = __uint_as_float(qc4.w << 16); q[15] = __uint_as_float(qc4.w & 0xFFFF0000u);
            q[16] = __uint_as_float(q16u << 16);
            float d0 = sv[0]*q[0], d1 = sv[1]*q[1], d2 = sv[2]*q[2], d3 = sv[3]*q[3];
            #pragma unroll
            for (int i = 4; i < 16; i += 4) {
                d0 = fmaf(sv[i+0], q[i+0], d0);
                d1 = fmaf(sv[i+1], q[i+1], d1);
                d2 = fmaf(sv[i+2], q[i+2], d2);
                d3 = fmaf(sv[i+3], q[i+3], d3);
            }
            d0 = fmaf(sv[16], q[16], d0);
            float nw = ((d0 + d1) + (d2 + d3)) * sc;
            w = active ? nw : 0.f;
            K += me + kc;
        }
        float s = w;
        #pragma unroll
        for (int off = 32; off > 0; off >>= 1) s += __shfl_xor(s, off, 64);
        if (lane == 0) s_denom = logf(s) + (float)K * LN2 + m0;
    }
    __syncthreads();

    if (tid == 0) {
        float ts = r0[0]+r0[1]+r0[2]+r0[3];
        float es = r1[0]+r1[1]+r1[2]+r1[3];
        int   ms = r2[0]+r2[1]+r2[2]+r2[3];
        int lt = tg[ms - 1];
        float le = (mp[T_-1] > 0) ? ip[(size_t)(T_-1)*N_ + lt] : 0.f;
        atomicAdd(out, ts + es + le - s_denom);
    }
}

extern "C" void kernel_launch(void* const* d_in, const int* in_sizes, int n_in,
                              void* d_out, int out_size, void* d_ws, size_t ws_size,
                              hipStream_t stream)
{
    const float* inputs    = (const float*)d_in[0];
    const int*   tags      = (const int*)  d_in[1];
    const float* hiddens   = (const float*)d_in[2];
    const int*   mask      = (const int*)  d_in[3];
    const float* p_in      = (const float*)d_in[4];
    const float* p_cross   = (const float*)d_in[5];
    const float* p_out     = (const float*)d_in[6];
    const float* p_to_out  = (const float*)d_in[7];
    const float* p_from_out= (const float*)d_in[8];
    const float* w_attn    = (const float*)d_in[9];
    const float* b_attn    = (const float*)d_in[10];
    float* out = (float*)d_out;
    float* ws  = (float*)d_ws;

    float* trans = ws;                               // 289 f32 @ byte 0
    int*   Kbuf  = (int*)(ws + 1024);                // byte 4096, up to 32 KB
    unsigned short* Qbuf = (unsigned short*)(ws + 16384);  // byte 65536

    const size_t need32 = (size_t)16384*4 + (size_t)B_*32*QMAT*2;  // ~6.9 MB
    const int nch = (ws_size >= need32) ? 32 : 16;

    (void)hipMemsetAsync(d_out, 0, sizeof(float), stream);
    hipLaunchKernelGGL(build_trans_k, dim3(1), dim3(256), 0, stream,
                       hiddens, p_in, p_cross, p_out, p_to_out, p_from_out,
                       w_attn, b_attn, trans);
    if (nch == 32)
        hipLaunchKernelGGL((phaseA_k<32>), dim3(B_*32), dim3(64), 0, stream,
                           inputs, mask, trans, Qbuf, Kbuf);
    else
        hipLaunchKernelGGL((phaseA_k<16>), dim3(B_*16), dim3(64), 0, stream,
                           inputs, mask, trans, Qbuf, Kbuf);
    hipLaunchKernelGGL(tail_k, dim3(B_), dim3(256), 0, stream,
                       inputs, tags, mask, trans, Qbuf, Kbuf, out, nch);
}

// Round 12
// 188.684 us; speedup vs baseline: 1.0243x; 1.0243x over previous
//
#include <hip/hip_runtime.h>
#include <math.h>

#define B_ 256
#define T_ 2048
#define N_ 17
#define LOG2E 1.44269504088896340736f
#define LN2   0.69314718055994530942f
#define QROW 24          // shorts per stored Q row
#define QMAT 416         // shorts per stored Q matrix

typedef short bf16x8 __attribute__((ext_vector_type(8)));
typedef float f32x16 __attribute__((ext_vector_type(16)));
typedef float v2f __attribute__((ext_vector_type(2)));

__device__ __forceinline__ float rlf(float v, int i) {
    return __int_as_float(__builtin_amdgcn_readlane(__float_as_int(v), i));
}
__device__ __forceinline__ float fexp2(float x) {
    float r;
    asm("v_exp_f32 %0, %1" : "=v"(r) : "v"(x));
    return r;
}
__device__ __forceinline__ float fmax3(float a, float b, float c) {
    return fmaxf(fmaxf(a, b), c);
}
// pack two f32 into bf16x2 (truncation — products are positive, bias tiny)
__device__ __forceinline__ unsigned pack_bf16(float lo, float hi) {
    return __builtin_amdgcn_perm(__float_as_uint(hi), __float_as_uint(lo), 0x07060302u);
}

// ---------------- kernel 1: build 17x17 log-transition matrix ----------------
__global__ __launch_bounds__(256) void build_trans_k(
    const float* __restrict__ hiddens, const float* __restrict__ p_in,
    const float* __restrict__ p_cross, const float* __restrict__ p_out,
    const float* __restrict__ p_to_out, const float* __restrict__ p_from_out,
    const float* __restrict__ w_attn, const float* __restrict__ b_attn,
    float* __restrict__ trans)
{
    __shared__ float partial[32][8];
    __shared__ float att[8][4];
    int tid = threadIdx.x;
    int pair = tid >> 3, sub = tid & 7;
    int e = pair >> 2, a = pair & 3;
    float acc = 0.f;
    for (int h = sub; h < 768; h += 8)
        acc += hiddens[e*768 + h] * w_attn[h*4 + a];
    partial[pair][sub] = acc;
    __syncthreads();
    if (tid < 32) {
        float s = 0.f;
        for (int k2 = 0; k2 < 8; ++k2) s += partial[tid][k2];
        att[tid>>2][tid&3] = s + b_attn[tid&3];
    }
    __syncthreads();
    if (tid == 0) {
        float t1[8][4], t2[8][4];
        for (int a2 = 0; a2 < 4; ++a2) {
            float m = -1e30f;
            for (int e2 = 0; e2 < 8; ++e2) m = fmaxf(m, att[e2][a2]);
            float s = 0.f;
            for (int e2 = 0; e2 < 8; ++e2) { t1[e2][a2] = expf(att[e2][a2] - m); s += t1[e2][a2]; }
            for (int e2 = 0; e2 < 8; ++e2) t1[e2][a2] /= s;
        }
        for (int e2 = 0; e2 < 8; ++e2) {
            float m = -1e30f;
            for (int a2 = 0; a2 < 4; ++a2) m = fmaxf(m, t1[e2][a2]*10.f);
            float s = 0.f;
            for (int a2 = 0; a2 < 4; ++a2) { t2[e2][a2] = expf(t1[e2][a2]*10.f - m); s += t2[e2][a2]; }
            for (int a2 = 0; a2 < 4; ++a2) t2[e2][a2] /= s;
        }
        trans[0] = p_out[0];
        for (int c = 0; c < 16; ++c) trans[0*N_ + 1 + c] = p_from_out[c & 1];
        for (int r = 0; r < 16; ++r) trans[(1+r)*N_ + 0] = p_to_out[r & 1];
        for (int eb = 0; eb < 8; ++eb)
        for (int r = 0; r < 2; ++r)
        for (int ec = 0; ec < 8; ++ec)
        for (int c = 0; c < 2; ++c) {
            float v;
            if (eb == ec) {
                v = 0.f;
                for (int a2 = 0; a2 < 4; ++a2) v += p_in[a2*4 + r*2 + c] * t2[eb][a2];
                v *= 0.25f;
            } else v = p_cross[r*2 + c];
            trans[(1 + eb*2 + r)*N_ + (1 + ec*2 + c)] = v;
        }
    }
}

// ---------------- kernel 2: phase A — per-chunk product matrices via MFMA ----
// Q <- diag(e_t)*T~^T * Q, MFMA 32x32x16 bf16 pair per unmasked step.
// C-layout: col=lane&31, row=(reg&3)+8*(reg>>2)+4*(lane>>5).
// MASKED steps are skipped via wave-uniform branch (exact identity; no
// cndmask select path).  b2 = pack(acc[8],0) UNCONDITIONALLY: for h=1 lanes
// acc[8] is row 20 of Q, and rows >=17 stay identically zero because every A
// operand zeroes rows m>=17 and masked steps never touch acc.
__device__ __forceinline__ f32x16 pa_step_f(
    const f32x16& acc, const f32x16& fz, float ev,
    const v2f* TA, float TA8x)
{
    float e = fexp2(ev * LOG2E);
    v2f ee; ee.x = e; ee.y = e;
    v2f s0 = TA[0]*ee, s1 = TA[1]*ee, s2 = TA[2]*ee, s3 = TA[3]*ee;
    float s8x = TA8x * e;
    union { unsigned u[4]; bf16x8 v; } a1, a2, b1, b2;
    a1.u[0] = pack_bf16(s0.x, s0.y);
    a1.u[1] = pack_bf16(s1.x, s1.y);
    a1.u[2] = pack_bf16(s2.x, s2.y);
    a1.u[3] = pack_bf16(s3.x, s3.y);
    a2.u[0] = pack_bf16(s8x, 0.f);
    a2.u[1] = 0; a2.u[2] = 0; a2.u[3] = 0;
    b2.u[0] = pack_bf16(acc[8], 0.f);      // h=0: row16; h=1: row20 == 0
    b2.u[1] = 0; b2.u[2] = 0; b2.u[3] = 0;
    float x0=acc[0], x1=acc[1], x2=acc[2], x3=acc[3];
    float x4=acc[4], x5=acc[5], x6=acc[6], x7=acc[7];
    asm("v_permlane32_swap_b32 %0, %1" : "+v"(x4), "+v"(x0));
    asm("v_permlane32_swap_b32 %0, %1" : "+v"(x5), "+v"(x1));
    asm("v_permlane32_swap_b32 %0, %1" : "+v"(x6), "+v"(x2));
    asm("v_permlane32_swap_b32 %0, %1" : "+v"(x7), "+v"(x3));
    b1.u[0] = pack_bf16(x0, x1);
    b1.u[1] = pack_bf16(x2, x3);
    b1.u[2] = pack_bf16(x4, x5);
    b1.u[3] = pack_bf16(x6, x7);
    f32x16 d = __builtin_amdgcn_mfma_f32_32x32x16_bf16(a1.v, b1.v, fz, 0, 0, 0);
    d = __builtin_amdgcn_mfma_f32_32x32x16_bf16(a2.v, b2.v, d, 0, 0, 0);
    return d;
}

template <int NCH>
__global__ __launch_bounds__(64, 4) void phaseA_k(
    const float* __restrict__ inputs, const int* __restrict__ mask,
    const float* __restrict__ trans, unsigned short* __restrict__ Qout,
    int* __restrict__ Kout)
{
    constexpr int CL = T_ / NCH;
    constexpr int GR = CL / 8;
    const int gid = blockIdx.x;
    const int b = gid / NCH;
    const int c = gid % NCH;
    const int lane = threadIdx.x & 63;
    const int n = lane & 31;
    const int h = lane >> 5;

    v2f TA[4];
    #pragma unroll
    for (int r2 = 0; r2 < 4; ++r2) {
        int k0 = 8*h + 2*r2;
        TA[r2].x = (n < N_ && k0   < N_) ? expf(trans[k0*N_ + n])     : 0.f;
        TA[r2].y = (n < N_ && k0+1 < N_) ? expf(trans[(k0+1)*N_ + n]) : 0.f;
    }
    float TA8x = (n < N_ && h == 0) ? expf(trans[16*N_ + n]) : 0.f;

    f32x16 acc;
    #pragma unroll
    for (int r = 0; r < 16; ++r) {
        int R = (r & 3) + 8*(r >> 2) + 4*h;
        acc[r] = (R == n) ? 1.f : 0.f;
    }
    f32x16 fz;
    #pragma unroll
    for (int r = 0; r < 16; ++r) fz[r] = 0.f;

    const int t0 = c * CL;
    const float* ep = inputs + (size_t)b*T_*N_ + (n < N_ ? n : N_-1);
    const int*   mp = mask + (size_t)b*T_;

    float re[8]; int rm[8];
    #pragma unroll
    for (int p = 0; p < 8; ++p) {
        int t = t0 + p;
        re[p] = ep[(size_t)t * N_];
        rm[p] = (t == 0) ? 0 : mp[t];
    }
    const float* epn = ep + (size_t)(t0 + 8) * N_;
    const int*   mpn = mp + (t0 + 8);
    int K = 0;

#define PA_RESCALE                                                             \
    {                                                                          \
        float mxa = fmax3(acc[0], acc[1], acc[2]);                             \
        float mxb = fmax3(acc[3], acc[4], acc[5]);                             \
        float mx  = fmax3(acc[6], acc[7], acc[8]);                             \
        mx = fmax3(mx, mxa, mxb);                                              \
        _Pragma("unroll")                                                      \
        for (int off = 32; off > 0; off >>= 1)                                 \
            mx = fmaxf(mx, __shfl_xor(mx, off, 64));                           \
        int sexp = (int)(__float_as_uint(mx) >> 23) - 127;                     \
        float sc = __uint_as_float((unsigned)(127 - sexp) << 23);              \
        v2f scv; scv.x = sc; scv.y = sc;                                       \
        _Pragma("unroll")                                                      \
        for (int r = 0; r < 4; ++r) {                                          \
            v2f pr; pr.x = acc[2*r]; pr.y = acc[2*r+1];                        \
            pr = pr * scv;                                                     \
            acc[2*r] = pr.x; acc[2*r+1] = pr.y;                                \
        }                                                                      \
        acc[8] *= sc;                                                          \
        K += sexp;                                                             \
    }

    for (int g = 0; g < GR - 1; ++g) {
        #pragma unroll
        for (int u = 0; u < 8; ++u) {
            float ev = re[u]; int mv = rm[u];
            re[u] = epn[u * N_];
            rm[u] = mpn[u];
            if (__builtin_amdgcn_readfirstlane(mv) > 0)     // wave-uniform skip
                acc = pa_step_f(acc, fz, ev, TA, TA8x);
        }
        epn += 8 * N_; mpn += 8;
        PA_RESCALE
    }
    #pragma unroll
    for (int u = 0; u < 8; ++u) {
        float ev = re[u]; int mv = rm[u];
        if (__builtin_amdgcn_readfirstlane(mv) > 0)
            acc = pa_step_f(acc, fz, ev, TA, TA8x);
    }
    PA_RESCALE

    unsigned short* qb = Qout + (size_t)gid * QMAT;
    #pragma unroll
    for (int r = 0; r < 9; ++r) {
        int R = (r & 3) + 8*(r >> 2) + 4*h;
        if (R < N_ && n < N_)
            qb[R*QROW + n] = (unsigned short)(__float_as_uint(acc[r]) >> 16);
    }
    if (lane == 0) Kout[gid] = K;
}

// ---------------- kernel 3: fused tail — numer partials + combine + output ---
__global__ __launch_bounds__(256) void tail_k(
    const float* __restrict__ inputs, const int* __restrict__ tags,
    const int* __restrict__ mask, const float* __restrict__ trans,
    const unsigned short* __restrict__ Qin, const int* __restrict__ Kin,
    float* __restrict__ out, int nch)
{
    const int b = blockIdx.x, tid = threadIdx.x;
    const int* tg = tags + (size_t)b * T_;
    const int* mp = mask + (size_t)b * T_;
    const float* ip = inputs + (size_t)b * T_ * N_;

    // ---- numerator partial sums (all 256 threads) ----
    float tsum = 0.f, esum = 0.f; int msum = 0;
    for (int t = tid; t < T_ - 1; t += 256) {
        int g = tg[t], g2 = tg[t+1];
        int m1 = mp[t], m2 = mp[t+1];
        tsum += (m2 > 0) ? trans[g*N_ + g2] : 0.f;
        esum += (m1 > 0) ? ip[(size_t)t*N_ + g] : 0.f;
        msum += (m1 > 0) ? 1 : 0;
    }
    if (tid == 0) msum += (mp[T_-1] > 0) ? 1 : 0;
    #pragma unroll
    for (int off = 32; off > 0; off >>= 1) {
        tsum += __shfl_xor(tsum, off, 64);
        esum += __shfl_xor(esum, off, 64);
        msum += __shfl_xor(msum, off, 64);
    }
    __shared__ float r0[4], r1[4]; __shared__ int r2[4];
    __shared__ float s_denom;
    int wid = tid >> 6;
    if ((tid & 63) == 0) { r0[wid] = tsum; r1[wid] = esum; r2[wid] = msum; }
    __syncthreads();

    // ---- combine chunk matrices (wave 0 only) ----
    if (tid < 64) {
        const int lane = tid;
        const bool active = lane < N_;
        const int j = active ? lane : N_-1;
        float a0 = active ? ip[j] : -1e30f;
        float m0 = rlf(a0, 0);
        #pragma unroll
        for (int i = 1; i < N_; ++i) m0 = fmaxf(m0, rlf(a0, i));
        float w = active ? fexp2((a0 - m0)*LOG2E) : 0.f;
        int K = 0;
        for (int c = 0; c < nch; ++c) {
            const unsigned short* qr = Qin + (size_t)(b*nch + c)*QMAT + j*QROW;
            uint4 qa = *(const uint4*)qr;
            uint4 qc4 = *(const uint4*)(qr + 8);
            unsigned q16u = qr[16];
            int kc = Kin[b*nch + c];
            float sv[N_];
            #pragma unroll
            for (int i = 0; i < N_; ++i) sv[i] = rlf(w, i);
            unsigned mxb = __float_as_uint(sv[0]);
            #pragma unroll
            for (int i = 1; i < N_; ++i) { unsigned bi = __float_as_uint(sv[i]); if (bi > mxb) mxb = bi; }
            int me = (int)(mxb >> 23) - 127;
            float sc = __uint_as_float((unsigned)(127 - me) << 23);
            float q[N_];
            q[0]  = __uint_as_float(qa.x << 16);  q[1]  = __uint_as_float(qa.x & 0xFFFF0000u);
            q[2]  = __uint_as_float(qa.y << 16);  q[3]  = __uint_as_float(qa.y & 0xFFFF0000u);
            q[4]  = __uint_as_float(qa.z << 16);  q[5]  = __uint_as_float(qa.z & 0xFFFF0000u);
            q[6]  = __uint_as_float(qa.w << 16);  q[7]  = __uint_as_float(qa.w & 0xFFFF0000u);
            q[8]  = __uint_as_float(qc4.x << 16); q[9]  = __uint_as_float(qc4.x & 0xFFFF0000u);
            q[10] = __uint_as_float(qc4.y << 16); q[11] = __uint_as_float(qc4.y & 0xFFFF0000u);
            q[12] = __uint_as_float(qc4.z << 16); q[13] = __uint_as_float(qc4.z & 0xFFFF0000u);
            q[14] = __uint_as_float(qc4.w << 16); q[15] = __uint_as_float(qc4.w & 0xFFFF0000u);
            q[16] = __uint_as_float(q16u << 16);
            float d0 = sv[0]*q[0], d1 = sv[1]*q[1], d2 = sv[2]*q[2], d3 = sv[3]*q[3];
            #pragma unroll
            for (int i = 4; i < 16; i += 4) {
                d0 = fmaf(sv[i+0], q[i+0], d0);
                d1 = fmaf(sv[i+1], q[i+1], d1);
                d2 = fmaf(sv[i+2], q[i+2], d2);
                d3 = fmaf(sv[i+3], q[i+3], d3);
            }
            d0 = fmaf(sv[16], q[16], d0);
            float nw = ((d0 + d1) + (d2 + d3)) * sc;
            w = active ? nw : 0.f;
            K += me + kc;
        }
        float s = w;
        #pragma unroll
        for (int off = 32; off > 0; off >>= 1) s += __shfl_xor(s, off, 64);
        if (lane == 0) s_denom = logf(s) + (float)K * LN2 + m0;
    }
    __syncthreads();

    if (tid == 0) {
        float ts = r0[0]+r0[1]+r0[2]+r0[3];
        float es = r1[0]+r1[1]+r1[2]+r1[3];
        int   ms = r2[0]+r2[1]+r2[2]+r2[3];
        int lt = tg[ms - 1];
        float le = (mp[T_-1] > 0) ? ip[(size_t)(T_-1)*N_ + lt] : 0.f;
        atomicAdd(out, ts + es + le - s_denom);
    }
}

extern "C" void kernel_launch(void* const* d_in, const int* in_sizes, int n_in,
                              void* d_out, int out_size, void* d_ws, size_t ws_size,
                              hipStream_t stream)
{
    const float* inputs    = (const float*)d_in[0];
    const int*   tags      = (const int*)  d_in[1];
    const float* hiddens   = (const float*)d_in[2];
    const int*   mask      = (const int*)  d_in[3];
    const float* p_in      = (const float*)d_in[4];
    const float* p_cross   = (const float*)d_in[5];
    const float* p_out     = (const float*)d_in[6];
    const float* p_to_out  = (const float*)d_in[7];
    const float* p_from_out= (const float*)d_in[8];
    const float* w_attn    = (const float*)d_in[9];
    const float* b_attn    = (const float*)d_in[10];
    float* out = (float*)d_out;
    float* ws  = (float*)d_ws;

    float* trans = ws;                               // 289 f32 @ byte 0
    int*   Kbuf  = (int*)(ws + 1024);                // byte 4096, up to 32 KB
    unsigned short* Qbuf = (unsigned short*)(ws + 16384);  // byte 65536

    const size_t need32 = (size_t)16384*4 + (size_t)B_*32*QMAT*2;  // ~6.9 MB
    const int nch = (ws_size >= need32) ? 32 : 16;

    (void)hipMemsetAsync(d_out, 0, sizeof(float), stream);
    hipLaunchKernelGGL(build_trans_k, dim3(1), dim3(256), 0, stream,
                       hiddens, p_in, p_cross, p_out, p_to_out, p_from_out,
                       w_attn, b_attn, trans);
    if (nch == 32)
        hipLaunchKernelGGL((phaseA_k<32>), dim3(B_*32), dim3(64), 0, stream,
                           inputs, mask, trans, Qbuf, Kbuf);
    else
        hipLaunchKernelGGL((phaseA_k<16>), dim3(B_*16), dim3(64), 0, stream,
                           inputs, mask, trans, Qbuf, Kbuf);
    hipLaunchKernelGGL(tail_k, dim3(B_), dim3(256), 0, stream,
                       inputs, tags, mask, trans, Qbuf, Kbuf, out, nch);
}